// Round 11
// baseline (404.483 us; speedup 1.0000x reference)
//
#include <hip/hip_runtime.h>

// MHA forward: B=2, S=2048, D=1024, H=16, dk=64.
// Pipeline: cvt x,W -> bf16; fused QKV GEMM (V transposed out) -> flash attn -> O GEMM.
// ws layout (bf16 elems): Qb[4M] Kb[4M] Vt[4M] Xb/Ctx[4M] (+Wb[4x1M] if ws >= 40MB).
// R11: attention is barrier-free and K/V-LDS-free: MFMA B-fragments are loaded
// straight from global (L1/L2-resident, per-head KV = 512KB) with register
// double-buffering: K(t+1) issued right after QK^T(t), V(t) issued at tile start.
// Only per-wave P goes through LDS. Tests the barrier/LDS-chain hypothesis.

#define D_MODEL 1024
#define SEQ     2048
#define NHEAD   16
#define DKH     64
#define MROWS   4096   // B*S

typedef __attribute__((ext_vector_type(8))) short bf16x8;
typedef __attribute__((ext_vector_type(4))) float f32x4;

__device__ __forceinline__ unsigned short f2bf(float f) {
    union { float f; unsigned u; } v; v.f = f;
    unsigned r = (v.u + 0x7fffu + ((v.u >> 16) & 1u)) >> 16;   // RNE
    return (unsigned short)r;
}
__device__ __forceinline__ unsigned short f2bf_fast(float f) {  // round-half-up (P in [0,1])
    union { float f; unsigned u; } v; v.f = f;
    return (unsigned short)((v.u + 0x8000u) >> 16);
}
__device__ __forceinline__ unsigned long long pack4(float4 v) {
    return (unsigned long long)f2bf(v.x)
         | ((unsigned long long)f2bf(v.y) << 16)
         | ((unsigned long long)f2bf(v.z) << 32)
         | ((unsigned long long)f2bf(v.w) << 48);
}

// XOR swizzle: spreads 128B-stride rows across banks; preserves 16B alignment.
__device__ __forceinline__ int swz(int row, int byte) { return byte ^ ((row & 7) << 4); }

// DPP 16-lane butterfly reduce (reduce group = one DPP row of 16 lanes).
#define DPP_F(x, ctrl) __builtin_bit_cast(float, __builtin_amdgcn_mov_dpp(__builtin_bit_cast(int, (x)), (ctrl), 0xf, 0xf, true))
__device__ __forceinline__ float redmax16(float x) {
    x = fmaxf(x, DPP_F(x, 0xB1));
    x = fmaxf(x, DPP_F(x, 0x4E));
    x = fmaxf(x, DPP_F(x, 0x141));
    x = fmaxf(x, DPP_F(x, 0x140));
    return x;
}
__device__ __forceinline__ float redsum16(float x) {
    x += DPP_F(x, 0xB1);
    x += DPP_F(x, 0x4E);
    x += DPP_F(x, 0x141);
    x += DPP_F(x, 0x140);
    return x;
}

// ---------------------------------------------------------------------------
// fp32 -> bf16 bulk converts
// ---------------------------------------------------------------------------
__global__ __launch_bounds__(256) void cvt_bf16(const float* __restrict__ src,
                                                unsigned short* __restrict__ dst, int n4)
{
    int i = blockIdx.x * 256 + threadIdx.x;
    if (i < n4) {
        float4 v = reinterpret_cast<const float4*>(src)[i];
        reinterpret_cast<unsigned long long*>(dst)[i] = pack4(v);
    }
}
__global__ __launch_bounds__(256) void cvt_w4(const float* s0, const float* s1,
                                              const float* s2, const float* s3,
                                              unsigned short* d0, unsigned short* d1,
                                              unsigned short* d2, unsigned short* d3, int n4)
{
    const float* s = (blockIdx.z == 0) ? s0 : (blockIdx.z == 1) ? s1 : (blockIdx.z == 2) ? s2 : s3;
    unsigned short* d = (blockIdx.z == 0) ? d0 : (blockIdx.z == 1) ? d1 : (blockIdx.z == 2) ? d2 : d3;
    int i = blockIdx.x * 256 + threadIdx.x;
    if (i < n4) {
        float4 v = reinterpret_cast<const float4*>(s)[i];
        reinterpret_cast<unsigned long long*>(d)[i] = pack4(v);
    }
}

// ---------------------------------------------------------------------------
// Shared GEMM body: C[128x128 tile] = (A @ W^T + bias) * oscale, K = 1024.
// Pipeline: sync; storeLDS; sync; issue next loads; compute.
// ---------------------------------------------------------------------------
template<bool W_BF16>
__device__ __forceinline__ void gemm_body(const unsigned short* __restrict__ Ap,
                                          const void* __restrict__ Wp,
                                          const float* __restrict__ bias,
                                          void* __restrict__ Cp, float oscale,
                                          bool outT, bool outBF16,
                                          int m0, int n0, unsigned char* lds)
{
    const int tid = threadIdx.x;
    const int w = tid >> 6, l = tid & 63;
    const int wm = (w >> 1) * 64, wn = (w & 1) * 64;
    const int lr = l & 15, lk = l >> 4;

    f32x4 acc[4][4] = {};
    int4 ra[4], rwb[4];
    float4 rwf[8];

    auto loadA = [&](int k0) {
        #pragma unroll
        for (int i = 0; i < 4; i++) {
            int c = tid + i * 256;
            int row = c >> 3, col8 = c & 7;
            ra[i] = *reinterpret_cast<const int4*>(Ap + (size_t)(m0 + row) * D_MODEL + k0 + col8 * 8);
        }
    };
    auto loadW = [&](int k0) {
        if constexpr (W_BF16) {
            const unsigned short* W = (const unsigned short*)Wp;
            #pragma unroll
            for (int i = 0; i < 4; i++) {
                int c = tid + i * 256;
                int row = c >> 3, col8 = c & 7;
                rwb[i] = *reinterpret_cast<const int4*>(W + (size_t)(n0 + row) * D_MODEL + k0 + col8 * 8);
            }
        } else {
            const float* W = (const float*)Wp;
            #pragma unroll
            for (int i = 0; i < 8; i++) {
                int c = tid + i * 256;
                int row = c >> 4, col4 = c & 15;
                rwf[i] = *reinterpret_cast<const float4*>(W + (size_t)(n0 + row) * D_MODEL + k0 + col4 * 4);
            }
        }
    };
    auto storeT = [&]() {
        #pragma unroll
        for (int i = 0; i < 4; i++) {
            int c = tid + i * 256;
            int row = c >> 3, col8 = c & 7;
            *reinterpret_cast<int4*>(lds + swz(row, row * 128 + col8 * 16)) = ra[i];
        }
        if constexpr (W_BF16) {
            #pragma unroll
            for (int i = 0; i < 4; i++) {
                int c = tid + i * 256;
                int row = c >> 3, col8 = c & 7;
                *reinterpret_cast<int4*>(lds + 16384 + swz(row, row * 128 + col8 * 16)) = rwb[i];
            }
        } else {
            #pragma unroll
            for (int i = 0; i < 8; i++) {
                int c = tid + i * 256;
                int row = c >> 4, col4 = c & 15;
                *reinterpret_cast<unsigned long long*>(lds + 16384 + swz(row, row * 128 + col4 * 8)) = pack4(rwf[i]);
            }
        }
    };

    loadA(0); loadW(0);
    for (int k0 = 0; k0 < D_MODEL; k0 += 64) {
        __syncthreads();
        storeT();
        __syncthreads();
        if (k0 + 64 < D_MODEL) { loadA(k0 + 64); loadW(k0 + 64); }  // latency hides under compute
        #pragma unroll
        for (int ks = 0; ks < 2; ks++) {
            bf16x8 af[4], bfr[4];
            #pragma unroll
            for (int rt = 0; rt < 4; rt++) {
                int row = wm + rt * 16 + lr;
                af[rt] = *reinterpret_cast<const bf16x8*>(lds + swz(row, row * 128 + ks * 64 + lk * 16));
            }
            #pragma unroll
            for (int ct = 0; ct < 4; ct++) {
                int row = wn + ct * 16 + lr;
                bfr[ct] = *reinterpret_cast<const bf16x8*>(lds + 16384 + swz(row, row * 128 + ks * 64 + lk * 16));
            }
            #pragma unroll
            for (int rt = 0; rt < 4; rt++)
                #pragma unroll
                for (int ct = 0; ct < 4; ct++)
                    acc[rt][ct] = __builtin_amdgcn_mfma_f32_16x16x32_bf16(af[rt], bfr[ct], acc[rt][ct], 0, 0, 0);
        }
    }
    #pragma unroll
    for (int ct = 0; ct < 4; ct++) {
        int n = n0 + wn + ct * 16 + lr;
        float bv = bias[n];
        #pragma unroll
        for (int rt = 0; rt < 4; rt++) {
            #pragma unroll
            for (int j = 0; j < 4; j++) {
                int m = m0 + wm + rt * 16 + lk * 4 + j;
                float v = (acc[rt][ct][j] + bv) * oscale;
                if (outT)
                    ((unsigned short*)Cp)[(size_t)n * MROWS + m] = f2bf(v);
                else if (outBF16)
                    ((unsigned short*)Cp)[(size_t)m * D_MODEL + n] = f2bf(v);
                else
                    ((float*)Cp)[(size_t)m * D_MODEL + n] = v;
            }
        }
    }
}

// Fused QKV GEMM: blockIdx.z in {0,1,2} -> (Q, K, V^T).
template<bool W_BF16>
__global__ __launch_bounds__(256) void gemm_qkv(const unsigned short* __restrict__ Xb,
                                                const void* W0, const void* W1, const void* W2,
                                                const float* b0, const float* b1, const float* b2,
                                                void* C0, void* C1, void* C2, float qsc)
{
    __shared__ __align__(16) unsigned char lds[32768];
    const int z = blockIdx.z;
    const void* W = (z == 0) ? W0 : (z == 1) ? W1 : W2;
    const float* bias = (z == 0) ? b0 : (z == 1) ? b1 : b2;
    void* C = (z == 0) ? C0 : (z == 1) ? C1 : C2;
    gemm_body<W_BF16>(Xb, W, bias, C, (z == 0) ? qsc : 1.0f, z == 2, true,
                      blockIdx.y * 128, blockIdx.x * 128, lds);
}

// Single GEMM (output projection): fp32 out.
template<bool W_BF16>
__global__ __launch_bounds__(256) void gemm_o(const unsigned short* __restrict__ Ap,
                                              const void* __restrict__ Wp,
                                              const float* __restrict__ bias,
                                              void* __restrict__ Cp)
{
    __shared__ __align__(16) unsigned char lds[32768];
    gemm_body<W_BF16>(Ap, Wp, bias, Cp, 1.0f, false, false,
                      blockIdx.y * 128, blockIdx.x * 128, lds);
}

// ---------------------------------------------------------------------------
// Causal flash attention -- barrier-free, K/V-LDS-free, reg double-buffered.
// Grid: (S/64, B*H), 4 waves; wave owns 16 q-rows. KVBLK = 64.
// K fragments for tile t+1 issued right after QK^T(t); V fragments for tile t
// issued at tile start (consumed after softmax). KV is L1/L2-resident (512KB/head).
// Only per-wave P goes through LDS (private rows; lgkmcnt-only ordering).
// ---------------------------------------------------------------------------
__global__ __launch_bounds__(256) void attn_fwd(const unsigned short* __restrict__ Qb,
                                                const unsigned short* __restrict__ Kb,
                                                const unsigned short* __restrict__ Vt,
                                                unsigned short* __restrict__ Ctx)
{
    __shared__ __align__(16) unsigned char plds[4][16 * 144]; // per-wave P [16][64+8pad]

    const int tid = threadIdx.x, w = tid >> 6, l = tid & 63;
    const int lr = l & 15, lk = l >> 4;
    const int q0 = ((int)gridDim.x - 1 - (int)blockIdx.x) * 64;   // big blocks first
    const int b = blockIdx.y >> 4, h = blockIdx.y & 15;
    const size_t headoff = (size_t)b * SEQ * D_MODEL + (size_t)h * DKH;   // Q/K/Ctx
    const size_t vtoff   = (size_t)h * DKH * MROWS + (size_t)b * SEQ;     // Vt[h*64+d][b*2048+kv]
    const int qrow = q0 + w * 16;

    // Q fragments (A-operand; Q pre-scaled by 0.125*log2e in the Q-GEMM)
    bf16x8 aq[2];
    #pragma unroll
    for (int ks = 0; ks < 2; ks++)
        aq[ks] = *reinterpret_cast<const bf16x8*>(
            Qb + headoff + (size_t)(qrow + lr) * D_MODEL + ks * 32 + lk * 8);

    // per-lane base pointers for B-fragment loads (same addressing as the R7 passing kernel)
    const unsigned short* kp = Kb + headoff + (size_t)lr * D_MODEL + lk * 8;
    const unsigned short* vp = Vt + vtoff + (size_t)lr * MROWS + lk * 8;

    f32x4 o[4] = {};
    float m_i[4], l_i[4];
    #pragma unroll
    for (int j = 0; j < 4; j++) { m_i[j] = -INFINITY; l_i[j] = 0.f; }

    const int ntiles = q0 / 64 + 1;

    // ---- prologue: K fragments for tile 0 ----
    bf16x8 bk[4][2];
    #pragma unroll
    for (int ct = 0; ct < 4; ct++)
        #pragma unroll
        for (int ks = 0; ks < 2; ks++)
            bk[ct][ks] = *reinterpret_cast<const bf16x8*>(kp + (size_t)(ct * 16) * D_MODEL + ks * 32);

    for (int t = 0; t < ntiles; t++) {
        const int kv0 = t * 64;

        // ---- issue V(t) loads now; consumed after softmax (~400 cyc of cover) ----
        bf16x8 vb[4][2];
        #pragma unroll
        for (int dt = 0; dt < 4; dt++) {
            vb[dt][0] = *reinterpret_cast<const bf16x8*>(vp + (size_t)(dt * 16) * MROWS + kv0);
            vb[dt][1] = *reinterpret_cast<const bf16x8*>(vp + (size_t)(dt * 16) * MROWS + kv0 + 32);
        }

        // ---- S = Q K^T from preloaded K regs ----
        f32x4 s[4];
        #pragma unroll
        for (int ct = 0; ct < 4; ct++) {
            f32x4 a = {0.f, 0.f, 0.f, 0.f};
            a = __builtin_amdgcn_mfma_f32_16x16x32_bf16(aq[0], bk[ct][0], a, 0, 0, 0);
            a = __builtin_amdgcn_mfma_f32_16x16x32_bf16(aq[1], bk[ct][1], a, 0, 0, 0);
            s[ct] = a;
        }

        // ---- issue K(t+1) loads; consumed at next tile's QK^T (~700 cyc of cover) ----
        if (t + 1 < ntiles) {
            const int kvn = kv0 + 64;
            #pragma unroll
            for (int ct = 0; ct < 4; ct++)
                #pragma unroll
                for (int ks = 0; ks < 2; ks++)
                    bk[ct][ks] = *reinterpret_cast<const bf16x8*>(kp + (size_t)(kvn + ct * 16) * D_MODEL + ks * 32);
        }

        // ---- causal mask + online softmax (DPP reduces; raw v_exp_f32) ----
        const bool needmask = (kv0 + 63) > qrow;
        float mx[4] = {-INFINITY, -INFINITY, -INFINITY, -INFINITY};
        #pragma unroll
        for (int ct = 0; ct < 4; ct++) {
            #pragma unroll
            for (int j = 0; j < 4; j++) {
                float v = s[ct][j];
                if (needmask) {
                    int row = qrow + lk * 4 + j;
                    int col = kv0 + ct * 16 + lr;
                    if (col > row) v = -INFINITY;
                }
                s[ct][j] = v;
                mx[j] = fmaxf(mx[j], v);
            }
        }
        #pragma unroll
        for (int j = 0; j < 4; j++) {
            mx[j] = redmax16(mx[j]);
            float mnew = fmaxf(m_i[j], mx[j]);
            float corr = __builtin_amdgcn_exp2f(m_i[j] - mnew);
            m_i[j] = mnew;
            l_i[j] *= corr;
            #pragma unroll
            for (int dt = 0; dt < 4; dt++) o[dt][j] *= corr;
        }
        float rs[4] = {0.f, 0.f, 0.f, 0.f};
        #pragma unroll
        for (int ct = 0; ct < 4; ct++) {
            #pragma unroll
            for (int j = 0; j < 4; j++) {
                float p = __builtin_amdgcn_exp2f(s[ct][j] - m_i[j]);
                rs[j] += p;
                *reinterpret_cast<unsigned short*>(&plds[w][0] + (lk * 4 + j) * 144 + (ct * 16 + lr) * 2) = f2bf_fast(p);
            }
        }
        #pragma unroll
        for (int j = 0; j < 4; j++) l_i[j] += redsum16(rs[j]);

        // P write->read: same-wave DS ops are in-order; LDS-only wait, no vmcnt drain
        asm volatile("s_waitcnt lgkmcnt(0)" ::: "memory");

        // ---- O += P V (pa from LDS, vb from regs issued at tile start) ----
        bf16x8 pa[2];
        #pragma unroll
        for (int ks = 0; ks < 2; ks++)
            pa[ks] = *reinterpret_cast<const bf16x8*>(&plds[w][0] + lr * 144 + ks * 64 + lk * 16);
        #pragma unroll
        for (int dt = 0; dt < 4; dt++) {
            o[dt] = __builtin_amdgcn_mfma_f32_16x16x32_bf16(pa[0], vb[dt][0], o[dt], 0, 0, 0);
            o[dt] = __builtin_amdgcn_mfma_f32_16x16x32_bf16(pa[1], vb[dt][1], o[dt], 0, 0, 0);
        }
    }

    // ---- epilogue: normalize + store ctx (bf16) ----
    #pragma unroll
    for (int j = 0; j < 4; j++) {
        float inv = 1.0f / l_i[j];
        int row = qrow + lk * 4 + j;
        #pragma unroll
        for (int dt = 0; dt < 4; dt++)
            Ctx[headoff + (size_t)row * D_MODEL + dt * 16 + lr] = f2bf(o[dt][j] * inv);
    }
}

extern "C" void kernel_launch(void* const* d_in, const int* in_sizes, int n_in,
                              void* d_out, int out_size, void* d_ws, size_t ws_size,
                              hipStream_t stream)
{
    const float* x   = (const float*)d_in[0];
    const float* w_q = (const float*)d_in[2];
    const float* b_q = (const float*)d_in[3];
    const float* w_k = (const float*)d_in[4];
    const float* b_k = (const float*)d_in[5];
    const float* w_v = (const float*)d_in[6];
    const float* b_v = (const float*)d_in[7];
    const float* w_o = (const float*)d_in[8];
    const float* b_o = (const float*)d_in[9];

    const size_t SEG = (size_t)MROWS * D_MODEL;        // 4M elems
    const size_t WSEG = (size_t)D_MODEL * D_MODEL;     // 1M elems
    unsigned short* Qb  = (unsigned short*)d_ws;
    unsigned short* Kb  = Qb + SEG;
    unsigned short* Vt  = Kb + SEG;                    // [1024][4096] (transposed)
    unsigned short* Xb  = Vt + SEG;                    // x bf16; later reused as Ctx
    unsigned short* Ctx = Xb;                          // alias: attn overwrites after x consumed
    unsigned short* Wqb = Xb + SEG;
    unsigned short* Wkb = Wqb + WSEG;
    unsigned short* Wvb = Wkb + WSEG;
    unsigned short* Wob = Wvb + WSEG;
    const bool fullws = ws_size >= (4 * SEG + 4 * WSEG) * 2;   // 40 MB

    const float QSC = 0.125f * 1.44269504088896f;  // 1/sqrt(dk) * log2(e), folded into Q

    dim3 blk(256);
    dim3 qkvgrid(D_MODEL / 128, MROWS / 128, 3);   // (8, 32, 3)
    dim3 ogrid(D_MODEL / 128, MROWS / 128);        // (8, 32)
    dim3 agrid(SEQ / 64, 32);                      // (32, 32)

    hipLaunchKernelGGL(cvt_bf16, dim3(4096), blk, 0, stream, x, Xb, (int)(SEG / 4));
    if (fullws) {
        hipLaunchKernelGGL(cvt_w4, dim3(1024, 1, 4), blk, 0, stream,
                           w_q, w_k, w_v, w_o, Wqb, Wkb, Wvb, Wob, (int)(WSEG / 4));
        hipLaunchKernelGGL((gemm_qkv<true>), qkvgrid, blk, 0, stream, Xb,
                           (const void*)Wqb, (const void*)Wkb, (const void*)Wvb,
                           b_q, b_k, b_v, (void*)Qb, (void*)Kb, (void*)Vt, QSC);
        hipLaunchKernelGGL(attn_fwd, agrid, blk, 0, stream, Qb, Kb, Vt, Ctx);
        hipLaunchKernelGGL((gemm_o<true>), ogrid, blk, 0, stream, Ctx, (const void*)Wob, b_o, d_out);
    } else {
        hipLaunchKernelGGL((gemm_qkv<false>), qkvgrid, blk, 0, stream, Xb,
                           (const void*)w_q, (const void*)w_k, (const void*)w_v,
                           b_q, b_k, b_v, (void*)Qb, (void*)Kb, (void*)Vt, QSC);
        hipLaunchKernelGGL(attn_fwd, agrid, blk, 0, stream, Qb, Kb, Vt, Ctx);
        hipLaunchKernelGGL((gemm_o<false>), ogrid, blk, 0, stream, Ctx, (const void*)w_o, b_o, d_out);
    }
}

// Round 12
// 271.662 us; speedup vs baseline: 1.4889x; 1.4889x over previous
//
#include <hip/hip_runtime.h>

// MHA forward: B=2, S=2048, D=1024, H=16, dk=64.
// Pipeline: cvt x,W -> bf16; fused QKV GEMM (V transposed out) -> flash attn -> O GEMM.
// R12: attention rewritten to the 32x32 swapped-QK structure (S^T = mfma(K,Q)):
// lane owns ONE q-row; softmax is in-lane + one shfl_xor(32); P feeds PV directly
// from registers (kv-slot permutation consistent between P and V fragments).
// No P-LDS, no DPP reduce chains. K/V staging identical to the proven R5/R8 path.

#define D_MODEL 1024
#define SEQ     2048
#define NHEAD   16
#define DKH     64
#define MROWS   4096   // B*S

typedef __attribute__((ext_vector_type(8))) short bf16x8;
typedef __attribute__((ext_vector_type(4))) float f32x4;
typedef __attribute__((ext_vector_type(16))) float f32x16;
#define ZERO16 {0.f,0.f,0.f,0.f,0.f,0.f,0.f,0.f,0.f,0.f,0.f,0.f,0.f,0.f,0.f,0.f}

__device__ __forceinline__ unsigned short f2bf(float f) {
    union { float f; unsigned u; } v; v.f = f;
    unsigned r = (v.u + 0x7fffu + ((v.u >> 16) & 1u)) >> 16;   // RNE
    return (unsigned short)r;
}
__device__ __forceinline__ unsigned pack2_fast(float a, float b) {  // P in [0,1]
    unsigned ua = (__builtin_bit_cast(unsigned, a) + 0x8000u) >> 16;
    unsigned ub = (__builtin_bit_cast(unsigned, b) + 0x8000u) & 0xffff0000u;
    return ua | ub;
}
__device__ __forceinline__ unsigned long long pack4(float4 v) {
    return (unsigned long long)f2bf(v.x)
         | ((unsigned long long)f2bf(v.y) << 16)
         | ((unsigned long long)f2bf(v.z) << 32)
         | ((unsigned long long)f2bf(v.w) << 48);
}
__device__ __forceinline__ unsigned long long pack4f(float a, float b, float c, float d) {
    return (unsigned long long)f2bf(a)
         | ((unsigned long long)f2bf(b) << 16)
         | ((unsigned long long)f2bf(c) << 32)
         | ((unsigned long long)f2bf(d) << 48);
}

// XOR swizzle: spreads 128B-stride rows across banks; preserves 16B blocks.
__device__ __forceinline__ int swz(int row, int byte) { return byte ^ ((row & 7) << 4); }

// ---------------------------------------------------------------------------
// fp32 -> bf16 bulk converts
// ---------------------------------------------------------------------------
__global__ __launch_bounds__(256) void cvt_bf16(const float* __restrict__ src,
                                                unsigned short* __restrict__ dst, int n4)
{
    int i = blockIdx.x * 256 + threadIdx.x;
    if (i < n4) {
        float4 v = reinterpret_cast<const float4*>(src)[i];
        reinterpret_cast<unsigned long long*>(dst)[i] = pack4(v);
    }
}
__global__ __launch_bounds__(256) void cvt_w4(const float* s0, const float* s1,
                                              const float* s2, const float* s3,
                                              unsigned short* d0, unsigned short* d1,
                                              unsigned short* d2, unsigned short* d3, int n4)
{
    const float* s = (blockIdx.z == 0) ? s0 : (blockIdx.z == 1) ? s1 : (blockIdx.z == 2) ? s2 : s3;
    unsigned short* d = (blockIdx.z == 0) ? d0 : (blockIdx.z == 1) ? d1 : (blockIdx.z == 2) ? d2 : d3;
    int i = blockIdx.x * 256 + threadIdx.x;
    if (i < n4) {
        float4 v = reinterpret_cast<const float4*>(s)[i];
        reinterpret_cast<unsigned long long*>(d)[i] = pack4(v);
    }
}

// ---------------------------------------------------------------------------
// Shared GEMM body: C[128x128 tile] = (A @ W^T + bias) * oscale, K = 1024.
// ---------------------------------------------------------------------------
template<bool W_BF16>
__device__ __forceinline__ void gemm_body(const unsigned short* __restrict__ Ap,
                                          const void* __restrict__ Wp,
                                          const float* __restrict__ bias,
                                          void* __restrict__ Cp, float oscale,
                                          bool outT, bool outBF16,
                                          int m0, int n0, unsigned char* lds)
{
    const int tid = threadIdx.x;
    const int w = tid >> 6, l = tid & 63;
    const int wm = (w >> 1) * 64, wn = (w & 1) * 64;
    const int lr = l & 15, lk = l >> 4;

    f32x4 acc[4][4] = {};
    int4 ra[4], rwb[4];
    float4 rwf[8];

    auto loadA = [&](int k0) {
        #pragma unroll
        for (int i = 0; i < 4; i++) {
            int c = tid + i * 256;
            int row = c >> 3, col8 = c & 7;
            ra[i] = *reinterpret_cast<const int4*>(Ap + (size_t)(m0 + row) * D_MODEL + k0 + col8 * 8);
        }
    };
    auto loadW = [&](int k0) {
        if constexpr (W_BF16) {
            const unsigned short* W = (const unsigned short*)Wp;
            #pragma unroll
            for (int i = 0; i < 4; i++) {
                int c = tid + i * 256;
                int row = c >> 3, col8 = c & 7;
                rwb[i] = *reinterpret_cast<const int4*>(W + (size_t)(n0 + row) * D_MODEL + k0 + col8 * 8);
            }
        } else {
            const float* W = (const float*)Wp;
            #pragma unroll
            for (int i = 0; i < 8; i++) {
                int c = tid + i * 256;
                int row = c >> 4, col4 = c & 15;
                rwf[i] = *reinterpret_cast<const float4*>(W + (size_t)(n0 + row) * D_MODEL + k0 + col4 * 4);
            }
        }
    };
    auto storeT = [&]() {
        #pragma unroll
        for (int i = 0; i < 4; i++) {
            int c = tid + i * 256;
            int row = c >> 3, col8 = c & 7;
            *reinterpret_cast<int4*>(lds + swz(row, row * 128 + col8 * 16)) = ra[i];
        }
        if constexpr (W_BF16) {
            #pragma unroll
            for (int i = 0; i < 4; i++) {
                int c = tid + i * 256;
                int row = c >> 3, col8 = c & 7;
                *reinterpret_cast<int4*>(lds + 16384 + swz(row, row * 128 + col8 * 16)) = rwb[i];
            }
        } else {
            #pragma unroll
            for (int i = 0; i < 8; i++) {
                int c = tid + i * 256;
                int row = c >> 4, col4 = c & 15;
                *reinterpret_cast<unsigned long long*>(lds + 16384 + swz(row, row * 128 + col4 * 8)) = pack4(rwf[i]);
            }
        }
    };

    loadA(0); loadW(0);
    for (int k0 = 0; k0 < D_MODEL; k0 += 64) {
        __syncthreads();
        storeT();
        __syncthreads();
        if (k0 + 64 < D_MODEL) { loadA(k0 + 64); loadW(k0 + 64); }
        #pragma unroll
        for (int ks = 0; ks < 2; ks++) {
            bf16x8 af[4], bfr[4];
            #pragma unroll
            for (int rt = 0; rt < 4; rt++) {
                int row = wm + rt * 16 + lr;
                af[rt] = *reinterpret_cast<const bf16x8*>(lds + swz(row, row * 128 + ks * 64 + lk * 16));
            }
            #pragma unroll
            for (int ct = 0; ct < 4; ct++) {
                int row = wn + ct * 16 + lr;
                bfr[ct] = *reinterpret_cast<const bf16x8*>(lds + 16384 + swz(row, row * 128 + ks * 64 + lk * 16));
            }
            #pragma unroll
            for (int rt = 0; rt < 4; rt++)
                #pragma unroll
                for (int ct = 0; ct < 4; ct++)
                    acc[rt][ct] = __builtin_amdgcn_mfma_f32_16x16x32_bf16(af[rt], bfr[ct], acc[rt][ct], 0, 0, 0);
        }
    }
    #pragma unroll
    for (int ct = 0; ct < 4; ct++) {
        int n = n0 + wn + ct * 16 + lr;
        float bv = bias[n];
        #pragma unroll
        for (int rt = 0; rt < 4; rt++) {
            #pragma unroll
            for (int j = 0; j < 4; j++) {
                int m = m0 + wm + rt * 16 + lk * 4 + j;
                float v = (acc[rt][ct][j] + bv) * oscale;
                if (outT)
                    ((unsigned short*)Cp)[(size_t)n * MROWS + m] = f2bf(v);
                else if (outBF16)
                    ((unsigned short*)Cp)[(size_t)m * D_MODEL + n] = f2bf(v);
                else
                    ((float*)Cp)[(size_t)m * D_MODEL + n] = v;
            }
        }
    }
}

template<bool W_BF16>
__global__ __launch_bounds__(256) void gemm_qkv(const unsigned short* __restrict__ Xb,
                                                const void* W0, const void* W1, const void* W2,
                                                const float* b0, const float* b1, const float* b2,
                                                void* C0, void* C1, void* C2, float qsc)
{
    __shared__ __align__(16) unsigned char lds[32768];
    const int z = blockIdx.z;
    const void* W = (z == 0) ? W0 : (z == 1) ? W1 : W2;
    const float* bias = (z == 0) ? b0 : (z == 1) ? b1 : b2;
    void* C = (z == 0) ? C0 : (z == 1) ? C1 : C2;
    gemm_body<W_BF16>(Xb, W, bias, C, (z == 0) ? qsc : 1.0f, z == 2, true,
                      blockIdx.y * 128, blockIdx.x * 128, lds);
}

template<bool W_BF16>
__global__ __launch_bounds__(256) void gemm_o(const unsigned short* __restrict__ Ap,
                                              const void* __restrict__ Wp,
                                              const float* __restrict__ bias,
                                              void* __restrict__ Cp)
{
    __shared__ __align__(16) unsigned char lds[32768];
    gemm_body<W_BF16>(Ap, Wp, bias, Cp, 1.0f, false, false,
                      blockIdx.y * 128, blockIdx.x * 128, lds);
}

// ---------------------------------------------------------------------------
// Causal flash attention, swapped-QK 32x32 structure.
// Grid: (S/128, B*H), 256 thr = 4 waves; wave owns 32 q-rows (lane l&31 = one q).
// KVBLK=64. S^T = mfma(A=K, B=Q): lane holds 16 kv (x2 half-tiles) for its q;
// lane^32 holds the complementary kv -> softmax = in-lane tree + 1 shfl_xor(32).
// PV: O^T += mfma(A=V'(sigma-permuted kv chunks), B=P-from-regs). No P-LDS.
// K/V staged exactly as R5/R8 (int4 -> swizzled ds_write_b128, prefetch after barrier).
// ---------------------------------------------------------------------------
__global__ __launch_bounds__(256) void attn_fwd(const unsigned short* __restrict__ Qb,
                                                const unsigned short* __restrict__ Kb,
                                                const unsigned short* __restrict__ Vt,
                                                unsigned short* __restrict__ Ctx)
{
    __shared__ __align__(16) unsigned char klds[8192];   // K tile [64 kv][64 k]
    __shared__ __align__(16) unsigned char vlds[8192];   // V^T tile [64 d][64 kv]

    const int tid = threadIdx.x, w = tid >> 6, l = tid & 63;
    const int ql = l & 31, hi = l >> 5;
    const int q0 = ((int)gridDim.x - 1 - (int)blockIdx.x) * 128;   // big blocks first
    const int b = blockIdx.y >> 4, h = blockIdx.y & 15;
    const size_t headoff = (size_t)b * SEQ * D_MODEL + (size_t)h * DKH;   // Q/K/Ctx
    const size_t vtoff   = (size_t)h * DKH * MROWS + (size_t)b * SEQ;     // Vt[h*64+d][b*2048+kv]
    const int qrow0 = q0 + w * 32;
    const int qg = qrow0 + ql;            // this lane's q row

    // Q B-operand fragments: aq[c] = Q[qg][16c + 8hi .. +8]  (pre-scaled by QSC)
    bf16x8 aq[4];
    #pragma unroll
    for (int c = 0; c < 4; c++)
        aq[c] = *reinterpret_cast<const bf16x8*>(
            Qb + headoff + (size_t)qg * D_MODEL + c * 16 + hi * 8);

    f32x16 o0 = ZERO16, o1 = ZERO16;      // O^T: d = (r&3)+8*(r>>2)+4hi (+32 for o1)
    float m_s = -INFINITY, l_s = 0.f;

    const int row_s = tid >> 3, col8 = tid & 7;
    int4 kr[2], vr[2];
    auto load = [&](int t) {
        const int kv0 = t * 64;
        #pragma unroll
        for (int i = 0; i < 2; i++) {
            int row = row_s + i * 32;
            kr[i] = *reinterpret_cast<const int4*>(Kb + headoff + (size_t)(kv0 + row) * D_MODEL + col8 * 8);
            vr[i] = *reinterpret_cast<const int4*>(Vt + vtoff + (size_t)row * MROWS + kv0 + col8 * 8);
        }
    };
    auto store = [&]() {
        #pragma unroll
        for (int i = 0; i < 2; i++) {
            int row = row_s + i * 32;
            *reinterpret_cast<int4*>(klds + swz(row, row * 128 + col8 * 16)) = kr[i];
            *reinterpret_cast<int4*>(vlds + swz(row, row * 128 + col8 * 16)) = vr[i];
        }
    };

    const int ntiles = q0 / 64 + 2;       // covers kv < q0+128
    load(0);

    for (int t = 0; t < ntiles; t++) {
        const int kv0 = t * 64;
        __syncthreads();                  // all waves done reading previous tile
        store();
        __syncthreads();                  // tile visible
        if (t + 1 < ntiles) load(t + 1);  // prefetch hides under compute

        // ---- S^T = K Q^T : two 32-kv half-tiles, K=64 via 4 chained mfmas ----
        f32x16 s0 = ZERO16, s1 = ZERO16;
        #pragma unroll
        for (int c = 0; c < 4; c++) {
            bf16x8 ka0 = *reinterpret_cast<const bf16x8*>(klds + swz(ql,      ql * 128        + c * 32 + hi * 16));
            bf16x8 ka1 = *reinterpret_cast<const bf16x8*>(klds + swz(ql + 32, (ql + 32) * 128 + c * 32 + hi * 16));
            s0 = __builtin_amdgcn_mfma_f32_32x32x16_bf16(ka0, aq[c], s0, 0, 0, 0);
            s1 = __builtin_amdgcn_mfma_f32_32x32x16_bf16(ka1, aq[c], s1, 0, 0, 0);
        }

        // ---- causal mask + online softmax (in-lane; m,l are per-lane scalars) ----
        float mx = -INFINITY;
        const bool needmask = (kv0 + 63) > qrow0;   // wave-uniform
        if (needmask) {
            #pragma unroll
            for (int r = 0; r < 16; r++) {
                const int kvc = (r & 3) + 8 * (r >> 2);
                int kva = kv0 + kvc + 4 * hi;
                float v0 = s0[r]; if (kva > qg)      v0 = -INFINITY;
                float v1 = s1[r]; if (kva + 32 > qg) v1 = -INFINITY;
                s0[r] = v0; s1[r] = v1;
                mx = fmaxf(mx, fmaxf(v0, v1));
            }
        } else {
            #pragma unroll
            for (int r = 0; r < 16; r++)
                mx = fmaxf(mx, fmaxf(s0[r], s1[r]));
        }
        mx = fmaxf(mx, __shfl_xor(mx, 32, 64));
        float mnew = fmaxf(m_s, mx);
        float corr = __builtin_amdgcn_exp2f(m_s - mnew);
        m_s = mnew;
        l_s *= corr;
        #pragma unroll
        for (int r = 0; r < 16; r++) { o0[r] *= corr; o1[r] *= corr; }
        float rs = 0.f;
        #pragma unroll
        for (int r = 0; r < 16; r++) {
            float p0 = __builtin_amdgcn_exp2f(s0[r] - mnew);
            float p1 = __builtin_amdgcn_exp2f(s1[r] - mnew);
            s0[r] = p0; s1[r] = p1;
            rs += p0 + p1;
        }
        rs += __shfl_xor(rs, 32, 64);
        l_s += rs;

        // ---- O^T += V' P : P straight from regs (slot s=hi*8+e <-> kv=16j+(e&3)+8(e>>2)+4hi) ----
        #pragma unroll
        for (int j = 0; j < 4; j++) {
            union { bf16x8 v; unsigned u[4]; } pu;
            #pragma unroll
            for (int wd = 0; wd < 4; wd++) {
                const int r0 = 8 * (j & 1) + 2 * wd;
                float pa0, pa1;
                if (j < 2) { pa0 = s0[r0]; pa1 = s0[r0 + 1]; }
                else       { pa0 = s1[r0]; pa1 = s1[r0 + 1]; }
                pu.u[wd] = pack2_fast(pa0, pa1);
            }
            union { bf16x8 v; unsigned long long q[2]; } va0, va1;
            const int byte0 = ql * 128 + 32 * j + 8 * hi;
            va0.q[0] = *reinterpret_cast<const unsigned long long*>(vlds + swz(ql, byte0));
            va0.q[1] = *reinterpret_cast<const unsigned long long*>(vlds + swz(ql, byte0 + 16));
            const int row1 = ql + 32;
            const int byte1 = row1 * 128 + 32 * j + 8 * hi;
            va1.q[0] = *reinterpret_cast<const unsigned long long*>(vlds + swz(row1, byte1));
            va1.q[1] = *reinterpret_cast<const unsigned long long*>(vlds + swz(row1, byte1 + 16));
            o0 = __builtin_amdgcn_mfma_f32_32x32x16_bf16(va0.v, pu.v, o0, 0, 0, 0);
            o1 = __builtin_amdgcn_mfma_f32_32x32x16_bf16(va1.v, pu.v, o1, 0, 0, 0);
        }
    }

    // ---- epilogue: normalize + store ctx (bf16, 8B packed stores) ----
    float inv = 1.0f / l_s;
    #pragma unroll
    for (int g = 0; g < 4; g++) {
        const int d0 = 8 * g + 4 * hi;
        *reinterpret_cast<unsigned long long*>(Ctx + headoff + (size_t)qg * D_MODEL + d0) =
            pack4f(o0[4 * g] * inv, o0[4 * g + 1] * inv, o0[4 * g + 2] * inv, o0[4 * g + 3] * inv);
        *reinterpret_cast<unsigned long long*>(Ctx + headoff + (size_t)qg * D_MODEL + 32 + d0) =
            pack4f(o1[4 * g] * inv, o1[4 * g + 1] * inv, o1[4 * g + 2] * inv, o1[4 * g + 3] * inv);
    }
}

extern "C" void kernel_launch(void* const* d_in, const int* in_sizes, int n_in,
                              void* d_out, int out_size, void* d_ws, size_t ws_size,
                              hipStream_t stream)
{
    const float* x   = (const float*)d_in[0];
    const float* w_q = (const float*)d_in[2];
    const float* b_q = (const float*)d_in[3];
    const float* w_k = (const float*)d_in[4];
    const float* b_k = (const float*)d_in[5];
    const float* w_v = (const float*)d_in[6];
    const float* b_v = (const float*)d_in[7];
    const float* w_o = (const float*)d_in[8];
    const float* b_o = (const float*)d_in[9];

    const size_t SEG = (size_t)MROWS * D_MODEL;        // 4M elems
    const size_t WSEG = (size_t)D_MODEL * D_MODEL;     // 1M elems
    unsigned short* Qb  = (unsigned short*)d_ws;
    unsigned short* Kb  = Qb + SEG;
    unsigned short* Vt  = Kb + SEG;                    // [1024][4096] (transposed)
    unsigned short* Xb  = Vt + SEG;                    // x bf16; later reused as Ctx
    unsigned short* Ctx = Xb;                          // alias: attn overwrites after x consumed
    unsigned short* Wqb = Xb + SEG;
    unsigned short* Wkb = Wqb + WSEG;
    unsigned short* Wvb = Wkb + WSEG;
    unsigned short* Wob = Wvb + WSEG;
    const bool fullws = ws_size >= (4 * SEG + 4 * WSEG) * 2;   // 40 MB

    const float QSC = 0.125f * 1.44269504088896f;  // 1/sqrt(dk) * log2(e), folded into Q

    dim3 blk(256);
    dim3 qkvgrid(D_MODEL / 128, MROWS / 128, 3);   // (8, 32, 3)
    dim3 ogrid(D_MODEL / 128, MROWS / 128);        // (8, 32)
    dim3 agrid(SEQ / 128, 32);                     // (16, 32)

    hipLaunchKernelGGL(cvt_bf16, dim3(4096), blk, 0, stream, x, Xb, (int)(SEG / 4));
    if (fullws) {
        hipLaunchKernelGGL(cvt_w4, dim3(1024, 1, 4), blk, 0, stream,
                           w_q, w_k, w_v, w_o, Wqb, Wkb, Wvb, Wob, (int)(WSEG / 4));
        hipLaunchKernelGGL((gemm_qkv<true>), qkvgrid, blk, 0, stream, Xb,
                           (const void*)Wqb, (const void*)Wkb, (const void*)Wvb,
                           b_q, b_k, b_v, (void*)Qb, (void*)Kb, (void*)Vt, QSC);
        hipLaunchKernelGGL(attn_fwd, agrid, blk, 0, stream, Qb, Kb, Vt, Ctx);
        hipLaunchKernelGGL((gemm_o<true>), ogrid, blk, 0, stream, Ctx, (const void*)Wob, b_o, d_out);
    } else {
        hipLaunchKernelGGL((gemm_qkv<false>), qkvgrid, blk, 0, stream, Xb,
                           (const void*)w_q, (const void*)w_k, (const void*)w_v,
                           b_q, b_k, b_v, (void*)Qb, (void*)Kb, (void*)Vt, QSC);
        hipLaunchKernelGGL(attn_fwd, agrid, blk, 0, stream, Qb, Kb, Vt, Ctx);
        hipLaunchKernelGGL((gemm_o<false>), ogrid, blk, 0, stream, Ctx, (const void*)w_o, b_o, d_out);
    }
}

// Round 13
// 265.721 us; speedup vs baseline: 1.5222x; 1.0224x over previous
//
#include <hip/hip_runtime.h>

// MHA forward: B=2, S=2048, D=1024, H=16, dk=64.
// Pipeline: cvt x,W -> bf16; fused QKV GEMM (V transposed out) -> flash attn -> O GEMM.
// R13 change: OUT_T epilogue goes through an LDS transpose (reusing the staging
// buffer) and writes 256B-contiguous row segments. The old scalar 2B stores at
// 8KB stride caused 10x write amplification (262MB WRITE_SIZE vs 25MB ideal).

#define D_MODEL 1024
#define SEQ     2048
#define NHEAD   16
#define DKH     64
#define MROWS   4096   // B*S

typedef __attribute__((ext_vector_type(8))) short bf16x8;
typedef __attribute__((ext_vector_type(4))) float f32x4;
typedef __attribute__((ext_vector_type(16))) float f32x16;
#define ZERO16 {0.f,0.f,0.f,0.f,0.f,0.f,0.f,0.f,0.f,0.f,0.f,0.f,0.f,0.f,0.f,0.f}

__device__ __forceinline__ unsigned short f2bf(float f) {
    union { float f; unsigned u; } v; v.f = f;
    unsigned r = (v.u + 0x7fffu + ((v.u >> 16) & 1u)) >> 16;   // RNE
    return (unsigned short)r;
}
__device__ __forceinline__ unsigned pack2_fast(float a, float b) {  // P in [0,1]
    unsigned ua = (__builtin_bit_cast(unsigned, a) + 0x8000u) >> 16;
    unsigned ub = (__builtin_bit_cast(unsigned, b) + 0x8000u) & 0xffff0000u;
    return ua | ub;
}
__device__ __forceinline__ unsigned long long pack4(float4 v) {
    return (unsigned long long)f2bf(v.x)
         | ((unsigned long long)f2bf(v.y) << 16)
         | ((unsigned long long)f2bf(v.z) << 32)
         | ((unsigned long long)f2bf(v.w) << 48);
}
__device__ __forceinline__ unsigned long long pack4f(float a, float b, float c, float d) {
    return (unsigned long long)f2bf(a)
         | ((unsigned long long)f2bf(b) << 16)
         | ((unsigned long long)f2bf(c) << 32)
         | ((unsigned long long)f2bf(d) << 48);
}

// XOR swizzle: spreads 128B-stride rows across banks; preserves 16B blocks.
__device__ __forceinline__ int swz(int row, int byte) { return byte ^ ((row & 7) << 4); }

// ---------------------------------------------------------------------------
// fp32 -> bf16 bulk converts
// ---------------------------------------------------------------------------
__global__ __launch_bounds__(256) void cvt_bf16(const float* __restrict__ src,
                                                unsigned short* __restrict__ dst, int n4)
{
    int i = blockIdx.x * 256 + threadIdx.x;
    if (i < n4) {
        float4 v = reinterpret_cast<const float4*>(src)[i];
        reinterpret_cast<unsigned long long*>(dst)[i] = pack4(v);
    }
}
__global__ __launch_bounds__(256) void cvt_w4(const float* s0, const float* s1,
                                              const float* s2, const float* s3,
                                              unsigned short* d0, unsigned short* d1,
                                              unsigned short* d2, unsigned short* d3, int n4)
{
    const float* s = (blockIdx.z == 0) ? s0 : (blockIdx.z == 1) ? s1 : (blockIdx.z == 2) ? s2 : s3;
    unsigned short* d = (blockIdx.z == 0) ? d0 : (blockIdx.z == 1) ? d1 : (blockIdx.z == 2) ? d2 : d3;
    int i = blockIdx.x * 256 + threadIdx.x;
    if (i < n4) {
        float4 v = reinterpret_cast<const float4*>(s)[i];
        reinterpret_cast<unsigned long long*>(d)[i] = pack4(v);
    }
}

// ---------------------------------------------------------------------------
// Shared GEMM body: C[128x128 tile] = (A @ W^T + bias) * oscale, K = 1024.
// OUT_T epilogue: LDS transpose -> coalesced 256B row writes.
// ---------------------------------------------------------------------------
template<bool W_BF16>
__device__ __forceinline__ void gemm_body(const unsigned short* __restrict__ Ap,
                                          const void* __restrict__ Wp,
                                          const float* __restrict__ bias,
                                          void* __restrict__ Cp, float oscale,
                                          bool outT, bool outBF16,
                                          int m0, int n0, unsigned char* lds)
{
    const int tid = threadIdx.x;
    const int w = tid >> 6, l = tid & 63;
    const int wm = (w >> 1) * 64, wn = (w & 1) * 64;
    const int lr = l & 15, lk = l >> 4;

    f32x4 acc[4][4] = {};
    int4 ra[4], rwb[4];
    float4 rwf[8];

    auto loadA = [&](int k0) {
        #pragma unroll
        for (int i = 0; i < 4; i++) {
            int c = tid + i * 256;
            int row = c >> 3, col8 = c & 7;
            ra[i] = *reinterpret_cast<const int4*>(Ap + (size_t)(m0 + row) * D_MODEL + k0 + col8 * 8);
        }
    };
    auto loadW = [&](int k0) {
        if constexpr (W_BF16) {
            const unsigned short* W = (const unsigned short*)Wp;
            #pragma unroll
            for (int i = 0; i < 4; i++) {
                int c = tid + i * 256;
                int row = c >> 3, col8 = c & 7;
                rwb[i] = *reinterpret_cast<const int4*>(W + (size_t)(n0 + row) * D_MODEL + k0 + col8 * 8);
            }
        } else {
            const float* W = (const float*)Wp;
            #pragma unroll
            for (int i = 0; i < 8; i++) {
                int c = tid + i * 256;
                int row = c >> 4, col4 = c & 15;
                rwf[i] = *reinterpret_cast<const float4*>(W + (size_t)(n0 + row) * D_MODEL + k0 + col4 * 4);
            }
        }
    };
    auto storeT = [&]() {
        #pragma unroll
        for (int i = 0; i < 4; i++) {
            int c = tid + i * 256;
            int row = c >> 3, col8 = c & 7;
            *reinterpret_cast<int4*>(lds + swz(row, row * 128 + col8 * 16)) = ra[i];
        }
        if constexpr (W_BF16) {
            #pragma unroll
            for (int i = 0; i < 4; i++) {
                int c = tid + i * 256;
                int row = c >> 3, col8 = c & 7;
                *reinterpret_cast<int4*>(lds + 16384 + swz(row, row * 128 + col8 * 16)) = rwb[i];
            }
        } else {
            #pragma unroll
            for (int i = 0; i < 8; i++) {
                int c = tid + i * 256;
                int row = c >> 4, col4 = c & 15;
                *reinterpret_cast<unsigned long long*>(lds + 16384 + swz(row, row * 128 + col4 * 8)) = pack4(rwf[i]);
            }
        }
    };

    loadA(0); loadW(0);
    for (int k0 = 0; k0 < D_MODEL; k0 += 64) {
        __syncthreads();
        storeT();
        __syncthreads();
        if (k0 + 64 < D_MODEL) { loadA(k0 + 64); loadW(k0 + 64); }
        #pragma unroll
        for (int ks = 0; ks < 2; ks++) {
            bf16x8 af[4], bfr[4];
            #pragma unroll
            for (int rt = 0; rt < 4; rt++) {
                int row = wm + rt * 16 + lr;
                af[rt] = *reinterpret_cast<const bf16x8*>(lds + swz(row, row * 128 + ks * 64 + lk * 16));
            }
            #pragma unroll
            for (int ct = 0; ct < 4; ct++) {
                int row = wn + ct * 16 + lr;
                bfr[ct] = *reinterpret_cast<const bf16x8*>(lds + 16384 + swz(row, row * 128 + ks * 64 + lk * 16));
            }
            #pragma unroll
            for (int rt = 0; rt < 4; rt++)
                #pragma unroll
                for (int ct = 0; ct < 4; ct++)
                    acc[rt][ct] = __builtin_amdgcn_mfma_f32_16x16x32_bf16(af[rt], bfr[ct], acc[rt][ct], 0, 0, 0);
        }
    }
    if (outT) {
        // ---- transposed epilogue: LDS transpose -> coalesced row writes ----
        __syncthreads();   // staging buffer no longer needed
        #pragma unroll
        for (int ct = 0; ct < 4; ct++) {
            int n = wn + ct * 16 + lr;
            float bv = bias[n0 + n];
            #pragma unroll
            for (int rt = 0; rt < 4; rt++) {
                int m = wm + rt * 16 + lk * 4;
                unsigned long long pk = pack4f((acc[rt][ct][0] + bv) * oscale,
                                               (acc[rt][ct][1] + bv) * oscale,
                                               (acc[rt][ct][2] + bv) * oscale,
                                               (acc[rt][ct][3] + bv) * oscale);
                *reinterpret_cast<unsigned long long*>(lds + n * 256 + ((m * 2) ^ ((n & 7) << 4))) = pk;
            }
        }
        __syncthreads();
        #pragma unroll
        for (int i = 0; i < 8; i++) {
            int n = w * 32 + i * 4 + (l >> 4);     // 4 rows per instruction
            int mb = (l & 15) * 16;                // 16 lanes x 16B = full 256B row
            int4 v = *reinterpret_cast<const int4*>(lds + n * 256 + (mb ^ ((n & 7) << 4)));
            *reinterpret_cast<int4*>((unsigned short*)Cp + (size_t)(n0 + n) * MROWS + m0 + mb / 2) = v;
        }
    } else {
        #pragma unroll
        for (int ct = 0; ct < 4; ct++) {
            int n = n0 + wn + ct * 16 + lr;
            float bv = bias[n];
            #pragma unroll
            for (int rt = 0; rt < 4; rt++) {
                #pragma unroll
                for (int j = 0; j < 4; j++) {
                    int m = m0 + wm + rt * 16 + lk * 4 + j;
                    float v = (acc[rt][ct][j] + bv) * oscale;
                    if (outBF16)
                        ((unsigned short*)Cp)[(size_t)m * D_MODEL + n] = f2bf(v);
                    else
                        ((float*)Cp)[(size_t)m * D_MODEL + n] = v;
                }
            }
        }
    }
}

template<bool W_BF16>
__global__ __launch_bounds__(256) void gemm_qkv(const unsigned short* __restrict__ Xb,
                                                const void* W0, const void* W1, const void* W2,
                                                const float* b0, const float* b1, const float* b2,
                                                void* C0, void* C1, void* C2, float qsc)
{
    __shared__ __align__(16) unsigned char lds[32768];
    const int z = blockIdx.z;
    const void* W = (z == 0) ? W0 : (z == 1) ? W1 : W2;
    const float* bias = (z == 0) ? b0 : (z == 1) ? b1 : b2;
    void* C = (z == 0) ? C0 : (z == 1) ? C1 : C2;
    gemm_body<W_BF16>(Xb, W, bias, C, (z == 0) ? qsc : 1.0f, z == 2, true,
                      blockIdx.y * 128, blockIdx.x * 128, lds);
}

template<bool W_BF16>
__global__ __launch_bounds__(256) void gemm_o(const unsigned short* __restrict__ Ap,
                                              const void* __restrict__ Wp,
                                              const float* __restrict__ bias,
                                              void* __restrict__ Cp)
{
    __shared__ __align__(16) unsigned char lds[32768];
    gemm_body<W_BF16>(Ap, Wp, bias, Cp, 1.0f, false, false,
                      blockIdx.y * 128, blockIdx.x * 128, lds);
}

// ---------------------------------------------------------------------------
// Causal flash attention, swapped-QK 32x32 structure (unchanged from R12).
// ---------------------------------------------------------------------------
__global__ __launch_bounds__(256) void attn_fwd(const unsigned short* __restrict__ Qb,
                                                const unsigned short* __restrict__ Kb,
                                                const unsigned short* __restrict__ Vt,
                                                unsigned short* __restrict__ Ctx)
{
    __shared__ __align__(16) unsigned char klds[8192];   // K tile [64 kv][64 k]
    __shared__ __align__(16) unsigned char vlds[8192];   // V^T tile [64 d][64 kv]

    const int tid = threadIdx.x, w = tid >> 6, l = tid & 63;
    const int ql = l & 31, hi = l >> 5;
    const int q0 = ((int)gridDim.x - 1 - (int)blockIdx.x) * 128;   // big blocks first
    const int b = blockIdx.y >> 4, h = blockIdx.y & 15;
    const size_t headoff = (size_t)b * SEQ * D_MODEL + (size_t)h * DKH;   // Q/K/Ctx
    const size_t vtoff   = (size_t)h * DKH * MROWS + (size_t)b * SEQ;     // Vt[h*64+d][b*2048+kv]
    const int qrow0 = q0 + w * 32;
    const int qg = qrow0 + ql;            // this lane's q row

    // Q B-operand fragments: aq[c] = Q[qg][16c + 8hi .. +8]  (pre-scaled by QSC)
    bf16x8 aq[4];
    #pragma unroll
    for (int c = 0; c < 4; c++)
        aq[c] = *reinterpret_cast<const bf16x8*>(
            Qb + headoff + (size_t)qg * D_MODEL + c * 16 + hi * 8);

    f32x16 o0 = ZERO16, o1 = ZERO16;      // O^T: d = (r&3)+8*(r>>2)+4hi (+32 for o1)
    float m_s = -INFINITY, l_s = 0.f;

    const int row_s = tid >> 3, col8 = tid & 7;
    int4 kr[2], vr[2];
    auto load = [&](int t) {
        const int kv0 = t * 64;
        #pragma unroll
        for (int i = 0; i < 2; i++) {
            int row = row_s + i * 32;
            kr[i] = *reinterpret_cast<const int4*>(Kb + headoff + (size_t)(kv0 + row) * D_MODEL + col8 * 8);
            vr[i] = *reinterpret_cast<const int4*>(Vt + vtoff + (size_t)row * MROWS + kv0 + col8 * 8);
        }
    };
    auto store = [&]() {
        #pragma unroll
        for (int i = 0; i < 2; i++) {
            int row = row_s + i * 32;
            *reinterpret_cast<int4*>(klds + swz(row, row * 128 + col8 * 16)) = kr[i];
            *reinterpret_cast<int4*>(vlds + swz(row, row * 128 + col8 * 16)) = vr[i];
        }
    };

    const int ntiles = q0 / 64 + 2;       // covers kv < q0+128
    load(0);

    for (int t = 0; t < ntiles; t++) {
        const int kv0 = t * 64;
        __syncthreads();                  // all waves done reading previous tile
        store();
        __syncthreads();                  // tile visible
        if (t + 1 < ntiles) load(t + 1);  // prefetch hides under compute

        // ---- S^T = K Q^T : two 32-kv half-tiles, K=64 via 4 chained mfmas ----
        f32x16 s0 = ZERO16, s1 = ZERO16;
        #pragma unroll
        for (int c = 0; c < 4; c++) {
            bf16x8 ka0 = *reinterpret_cast<const bf16x8*>(klds + swz(ql,      ql * 128        + c * 32 + hi * 16));
            bf16x8 ka1 = *reinterpret_cast<const bf16x8*>(klds + swz(ql + 32, (ql + 32) * 128 + c * 32 + hi * 16));
            s0 = __builtin_amdgcn_mfma_f32_32x32x16_bf16(ka0, aq[c], s0, 0, 0, 0);
            s1 = __builtin_amdgcn_mfma_f32_32x32x16_bf16(ka1, aq[c], s1, 0, 0, 0);
        }

        // ---- causal mask + online softmax (in-lane; m,l are per-lane scalars) ----
        float mx = -INFINITY;
        const bool needmask = (kv0 + 63) > qrow0;   // wave-uniform
        if (needmask) {
            #pragma unroll
            for (int r = 0; r < 16; r++) {
                const int kvc = (r & 3) + 8 * (r >> 2);
                int kva = kv0 + kvc + 4 * hi;
                float v0 = s0[r]; if (kva > qg)      v0 = -INFINITY;
                float v1 = s1[r]; if (kva + 32 > qg) v1 = -INFINITY;
                s0[r] = v0; s1[r] = v1;
                mx = fmaxf(mx, fmaxf(v0, v1));
            }
        } else {
            #pragma unroll
            for (int r = 0; r < 16; r++)
                mx = fmaxf(mx, fmaxf(s0[r], s1[r]));
        }
        mx = fmaxf(mx, __shfl_xor(mx, 32, 64));
        float mnew = fmaxf(m_s, mx);
        float corr = __builtin_amdgcn_exp2f(m_s - mnew);
        m_s = mnew;
        l_s *= corr;
        #pragma unroll
        for (int r = 0; r < 16; r++) { o0[r] *= corr; o1[r] *= corr; }
        float rs = 0.f;
        #pragma unroll
        for (int r = 0; r < 16; r++) {
            float p0 = __builtin_amdgcn_exp2f(s0[r] - mnew);
            float p1 = __builtin_amdgcn_exp2f(s1[r] - mnew);
            s0[r] = p0; s1[r] = p1;
            rs += p0 + p1;
        }
        rs += __shfl_xor(rs, 32, 64);
        l_s += rs;

        // ---- O^T += V' P : P straight from regs (slot s=hi*8+e <-> kv=16j+(e&3)+8(e>>2)+4hi) ----
        #pragma unroll
        for (int j = 0; j < 4; j++) {
            union { bf16x8 v; unsigned u[4]; } pu;
            #pragma unroll
            for (int wd = 0; wd < 4; wd++) {
                const int r0 = 8 * (j & 1) + 2 * wd;
                float pa0, pa1;
                if (j < 2) { pa0 = s0[r0]; pa1 = s0[r0 + 1]; }
                else       { pa0 = s1[r0]; pa1 = s1[r0 + 1]; }
                pu.u[wd] = pack2_fast(pa0, pa1);
            }
            union { bf16x8 v; unsigned long long q[2]; } va0, va1;
            const int byte0 = ql * 128 + 32 * j + 8 * hi;
            va0.q[0] = *reinterpret_cast<const unsigned long long*>(vlds + swz(ql, byte0));
            va0.q[1] = *reinterpret_cast<const unsigned long long*>(vlds + swz(ql, byte0 + 16));
            const int row1 = ql + 32;
            const int byte1 = row1 * 128 + 32 * j + 8 * hi;
            va1.q[0] = *reinterpret_cast<const unsigned long long*>(vlds + swz(row1, byte1));
            va1.q[1] = *reinterpret_cast<const unsigned long long*>(vlds + swz(row1, byte1 + 16));
            o0 = __builtin_amdgcn_mfma_f32_32x32x16_bf16(va0.v, pu.v, o0, 0, 0, 0);
            o1 = __builtin_amdgcn_mfma_f32_32x32x16_bf16(va1.v, pu.v, o1, 0, 0, 0);
        }
    }

    // ---- epilogue: normalize + store ctx (bf16, 8B packed stores) ----
    float inv = 1.0f / l_s;
    #pragma unroll
    for (int g = 0; g < 4; g++) {
        const int d0 = 8 * g + 4 * hi;
        *reinterpret_cast<unsigned long long*>(Ctx + headoff + (size_t)qg * D_MODEL + d0) =
            pack4f(o0[4 * g] * inv, o0[4 * g + 1] * inv, o0[4 * g + 2] * inv, o0[4 * g + 3] * inv);
        *reinterpret_cast<unsigned long long*>(Ctx + headoff + (size_t)qg * D_MODEL + 32 + d0) =
            pack4f(o1[4 * g] * inv, o1[4 * g + 1] * inv, o1[4 * g + 2] * inv, o1[4 * g + 3] * inv);
    }
}

extern "C" void kernel_launch(void* const* d_in, const int* in_sizes, int n_in,
                              void* d_out, int out_size, void* d_ws, size_t ws_size,
                              hipStream_t stream)
{
    const float* x   = (const float*)d_in[0];
    const float* w_q = (const float*)d_in[2];
    const float* b_q = (const float*)d_in[3];
    const float* w_k = (const float*)d_in[4];
    const float* b_k = (const float*)d_in[5];
    const float* w_v = (const float*)d_in[6];
    const float* b_v = (const float*)d_in[7];
    const float* w_o = (const float*)d_in[8];
    const float* b_o = (const float*)d_in[9];

    const size_t SEG = (size_t)MROWS * D_MODEL;        // 4M elems
    const size_t WSEG = (size_t)D_MODEL * D_MODEL;     // 1M elems
    unsigned short* Qb  = (unsigned short*)d_ws;
    unsigned short* Kb  = Qb + SEG;
    unsigned short* Vt  = Kb + SEG;                    // [1024][4096] (transposed)
    unsigned short* Xb  = Vt + SEG;                    // x bf16; later reused as Ctx
    unsigned short* Ctx = Xb;                          // alias: attn overwrites after x consumed
    unsigned short* Wqb = Xb + SEG;
    unsigned short* Wkb = Wqb + WSEG;
    unsigned short* Wvb = Wkb + WSEG;
    unsigned short* Wob = Wvb + WSEG;
    const bool fullws = ws_size >= (4 * SEG + 4 * WSEG) * 2;   // 40 MB

    const float QSC = 0.125f * 1.44269504088896f;  // 1/sqrt(dk) * log2(e), folded into Q

    dim3 blk(256);
    dim3 qkvgrid(D_MODEL / 128, MROWS / 128, 3);   // (8, 32, 3)
    dim3 ogrid(D_MODEL / 128, MROWS / 128);        // (8, 32)
    dim3 agrid(SEQ / 128, 32);                     // (16, 32)

    hipLaunchKernelGGL(cvt_bf16, dim3(4096), blk, 0, stream, x, Xb, (int)(SEG / 4));
    if (fullws) {
        hipLaunchKernelGGL(cvt_w4, dim3(1024, 1, 4), blk, 0, stream,
                           w_q, w_k, w_v, w_o, Wqb, Wkb, Wvb, Wob, (int)(WSEG / 4));
        hipLaunchKernelGGL((gemm_qkv<true>), qkvgrid, blk, 0, stream, Xb,
                           (const void*)Wqb, (const void*)Wkb, (const void*)Wvb,
                           b_q, b_k, b_v, (void*)Qb, (void*)Kb, (void*)Vt, QSC);
        hipLaunchKernelGGL(attn_fwd, agrid, blk, 0, stream, Qb, Kb, Vt, Ctx);
        hipLaunchKernelGGL((gemm_o<true>), ogrid, blk, 0, stream, Ctx, (const void*)Wob, b_o, d_out);
    } else {
        hipLaunchKernelGGL((gemm_qkv<false>), qkvgrid, blk, 0, stream, Xb,
                           (const void*)w_q, (const void*)w_k, (const void*)w_v,
                           b_q, b_k, b_v, (void*)Qb, (void*)Kb, (void*)Vt, QSC);
        hipLaunchKernelGGL(attn_fwd, agrid, blk, 0, stream, Qb, Kb, Vt, Ctx);
        hipLaunchKernelGGL((gemm_o<false>), ogrid, blk, 0, stream, Ctx, (const void*)w_o, b_o, d_out);
    }
}